// Round 11
// baseline (321.636 us; speedup 1.0000x reference)
//
#include <hip/hip_runtime.h>
#include <hip/hip_bf16.h>

#define DIM 64
#define SCAN_B 256
#define NXCD 8

// ---------------- Kernel 0: detect edge_index element width ----------------
__global__ void detect_layout_kernel(const int* __restrict__ ei32,
                                     int* __restrict__ flag) {
  int v = ei32[2 * threadIdx.x + 1];
  unsigned long long m = __ballot(v != 0);
  if (threadIdx.x == 0) *flag = (m == 0ULL) ? 1 : 0;  // 1 => int64 layout
}

__device__ __forceinline__ int load_idx(const int* ei32, int is64, size_t pos) {
  return is64 ? ei32[2 * pos] : ei32[pos];
}

// ---------------- Kernel 1: h = relu(x @ W^T + b) ----------------
__global__ __launch_bounds__(256) void linear_relu_kernel(
    const float* __restrict__ x, const float* __restrict__ W,
    const float* __restrict__ b, float* __restrict__ h, int N) {
  __shared__ float Ws[DIM * DIM];
  __shared__ float bs[DIM];
  for (int i = threadIdx.x; i < DIM * DIM; i += 256) Ws[i] = W[i];
  if (threadIdx.x < DIM) bs[threadIdx.x] = b[threadIdx.x];
  __syncthreads();

  int row = blockIdx.x * 256 + threadIdx.x;
  if (row >= N) return;

  const float4* xr = (const float4*)(x + (size_t)row * DIM);
  float acc[DIM];
#pragma unroll
  for (int o = 0; o < DIM; ++o) acc[o] = bs[o];

#pragma unroll
  for (int i4 = 0; i4 < DIM / 4; ++i4) {
    float4 xv = xr[i4];
#pragma unroll
    for (int o = 0; o < DIM; ++o) {
      const float* wrow = &Ws[o * DIM + i4 * 4];
      acc[o] = fmaf(xv.x, wrow[0], acc[o]);
      acc[o] = fmaf(xv.y, wrow[1], acc[o]);
      acc[o] = fmaf(xv.z, wrow[2], acc[o]);
      acc[o] = fmaf(xv.w, wrow[3], acc[o]);
    }
  }

  float4* hr = (float4*)(h + (size_t)row * DIM);
#pragma unroll
  for (int o4 = 0; o4 < DIM / 4; ++o4) {
    float4 v;
    v.x = fmaxf(acc[o4 * 4 + 0], 0.0f);
    v.y = fmaxf(acc[o4 * 4 + 1], 0.0f);
    v.z = fmaxf(acc[o4 * 4 + 2], 0.0f);
    v.w = fmaxf(acc[o4 * 4 + 3], 0.0f);
    hr[o4] = v;
  }
}

// ---------------- Kernel 2: per-XCD histogram + rank ----------------
// Counter atomics go to THIS XCD's replica with workgroup scope: the atomic
// completes in the local (physically shared per-XCD) L2 and stays dirty
// there instead of writing through to HBM per op (the ~17 G-line/s wall that
// made hist ~94 us). Kernel-end release writes back 3.2 MB once.
// chunk_xcd[] records which replica each 256-edge chunk used, so place can
// reconstruct the global position.
__global__ __launch_bounds__(256) void hist_xcd_kernel(
    const int* __restrict__ ei32, const int* __restrict__ flag,
    int* __restrict__ counts8, int* __restrict__ rank,
    int* __restrict__ chunk_xcd, int N, int E) {
  unsigned int xcc;
  asm volatile("s_getreg_b32 %0, hwreg(HW_REG_XCC_ID)" : "=s"(xcc));
  xcc &= (NXCD - 1);
  if (threadIdx.x == 0) chunk_xcd[blockIdx.x] = (int)xcc;

  int e = blockIdx.x * 256 + threadIdx.x;
  if (e >= E) return;
  int src = load_idx(ei32, *flag, (size_t)e);
  int* ctr = counts8 + (size_t)xcc * N + src;
  int r = __hip_atomic_fetch_add(ctr, 1, __ATOMIC_RELAXED,
                                 __HIP_MEMORY_SCOPE_WORKGROUP);
  __builtin_nontemporal_store(r, &rank[e]);  // coalesced stream, nt ok
}

// ---------------- Scan: totals + per-XCD relative bases + exclusive scan ---
// Thread i: sum the 8 replicas of node i, overwrite each replica slot with
// the exclusive prefix (relbase8), emit total to ctot, then block-scan.
__global__ void scan1_kernel(int* __restrict__ counts8, int* __restrict__ ctot,
                             int* __restrict__ offsets,
                             int* __restrict__ partials, int N) {
  __shared__ int s[SCAN_B];
  int t = threadIdx.x;
  int i = blockIdx.x * SCAN_B + t;
  int total = 0;
  if (i < N) {
    int run = 0;
#pragma unroll
    for (int x = 0; x < NXCD; ++x) {
      size_t idx = (size_t)x * N + i;
      int c = counts8[idx];
      counts8[idx] = run;  // relbase (in-place; thread owns column i)
      run += c;
    }
    total = run;
    ctot[i] = total;
  }
  s[t] = total;
  __syncthreads();
  for (int off = 1; off < SCAN_B; off <<= 1) {
    int add = (t >= off) ? s[t - off] : 0;
    __syncthreads();
    s[t] += add;
    __syncthreads();
  }
  if (i < N) offsets[i] = s[t] - total;  // exclusive within block
  if (t == SCAN_B - 1) partials[blockIdx.x] = s[t];
}

__global__ void scan2_kernel(int* __restrict__ partials, int nb) {
  __shared__ int s[512];
  int t = threadIdx.x;
  int v = (t < nb) ? partials[t] : 0;
  s[t] = v;
  __syncthreads();
  for (int off = 1; off < 512; off <<= 1) {
    int add = (t >= off) ? s[t - off] : 0;
    __syncthreads();
    s[t] += add;
    __syncthreads();
  }
  if (t < nb) partials[t] = s[t] - v;  // exclusive
}

__global__ void scan3_kernel(int* __restrict__ offsets,
                             const int* __restrict__ partials, int N) {
  int i = blockIdx.x * SCAN_B + threadIdx.x;
  if (i < N) offsets[i] += partials[blockIdx.x];
}

// ---------------- Kernel 3: place (atomic-free scatter) ----------------
// pos = offsets[src] + relbase8[chunk's xcd][src] + rank[e].
// PLAIN store (no nontemporal): round-10 post-mortem showed nt forced 64B
// write-through per 4B store (106 MB WRITE, ~90 us). Write-back L2 with
// dword-masked writeback coalesces this to ~bucket size.
__global__ __launch_bounds__(256) void place_kernel(
    const int* __restrict__ ei32, const int* __restrict__ flag,
    const int* __restrict__ offsets, const int* __restrict__ counts8,
    const int* __restrict__ rank, const int* __restrict__ chunk_xcd,
    int* __restrict__ bucket, int N, int E) {
  int e = blockIdx.x * 256 + threadIdx.x;
  if (e >= E) return;
  int is64 = *flag;
  int xcd = chunk_xcd[blockIdx.x];
  int src = load_idx(ei32, is64, (size_t)e);
  int tgt = load_idx(ei32, is64, (size_t)E + e);
  int r = __builtin_nontemporal_load(&rank[e]);
  int pos = offsets[src] + counts8[(size_t)xcd * N + src] + r;
  bucket[pos] = tgt;
}

// ---------------- Kernel 4: per-node gather + mean ----------------
// One wave per node; lane = feature dim; 8 loads in flight per wave.
__global__ __launch_bounds__(256) void gather_kernel(
    const float* __restrict__ h, const int* __restrict__ offsets,
    const int* __restrict__ ctot, const int* __restrict__ bucket,
    float* __restrict__ out, int N) {
  int wid = (blockIdx.x * 256 + threadIdx.x) >> 6;
  int lane = threadIdx.x & 63;
  if (wid >= N) return;

  int deg = ctot[wid];
  int start = offsets[wid];
  float a0 = 0.f, a1 = 0.f, a2 = 0.f, a3 = 0.f;
  float a4 = 0.f, a5 = 0.f, a6 = 0.f, a7 = 0.f;

  for (int j0 = 0; j0 < deg; j0 += 64) {
    int m = min(deg - j0, 64);
    int t = (lane < m) ? __builtin_nontemporal_load(&bucket[start + j0 + lane])
                       : 0;
    int j = 0;
    for (; j + 8 <= m; j += 8) {
      int t0 = __shfl(t, j);
      int t1 = __shfl(t, j + 1);
      int t2 = __shfl(t, j + 2);
      int t3 = __shfl(t, j + 3);
      int t4 = __shfl(t, j + 4);
      int t5 = __shfl(t, j + 5);
      int t6 = __shfl(t, j + 6);
      int t7 = __shfl(t, j + 7);
      float v0 = h[(size_t)t0 * DIM + lane];
      float v1 = h[(size_t)t1 * DIM + lane];
      float v2 = h[(size_t)t2 * DIM + lane];
      float v3 = h[(size_t)t3 * DIM + lane];
      float v4 = h[(size_t)t4 * DIM + lane];
      float v5 = h[(size_t)t5 * DIM + lane];
      float v6 = h[(size_t)t6 * DIM + lane];
      float v7 = h[(size_t)t7 * DIM + lane];
      a0 += v0; a1 += v1; a2 += v2; a3 += v3;
      a4 += v4; a5 += v5; a6 += v6; a7 += v7;
    }
    for (; j < m; ++j) {
      int tj = __shfl(t, j);
      a0 += h[(size_t)tj * DIM + lane];
    }
  }

  float c = (float)max(deg, 1);
  float acc = ((a0 + a1) + (a2 + a3)) + ((a4 + a5) + (a6 + a7));
  __builtin_nontemporal_store(acc / c, &out[(size_t)wid * DIM + lane]);
}

extern "C" void kernel_launch(void* const* d_in, const int* in_sizes, int n_in,
                              void* d_out, int out_size, void* d_ws, size_t ws_size,
                              hipStream_t stream) {
  const float* x = (const float*)d_in[0];
  const int* ei32 = (const int*)d_in[1];
  const float* W = (const float*)d_in[2];
  const float* b = (const float*)d_in[3];

  const int N = in_sizes[0] / DIM;  // 100000
  const int E = in_sizes[1] / 2;    // 1600000

  float* out = (float*)d_out;
  // rank[] borrows d_out (free scratch until gather writes the final output).
  int* rank = (int*)d_out;

  // Workspace:
  // [bucket E][counts8 8N][ctot N][offsets N][partials 512][flag][chunk_xcd]
  // [h N*DIM]   — ~36.1 MB total
  const int eb = (E + 255) / 256;  // 6250
  char* p = (char*)d_ws;
  int* bucket = (int*)p;    p += (size_t)E * 4;
  int* counts8 = (int*)p;   p += (size_t)NXCD * N * 4;
  int* ctot = (int*)p;      p += (size_t)N * 4;
  int* offsets = (int*)p;   p += (size_t)N * 4;
  int* partials = (int*)p;  p += 512 * 4;
  int* flag = (int*)p;      p += 16;
  int* chunk_xcd = (int*)p; p += (size_t)eb * 4;
  p = (char*)(((uintptr_t)p + 15) & ~(uintptr_t)15);
  float* h = (float*)p;

  const int nb1 = (N + SCAN_B - 1) / SCAN_B;  // 391

  hipMemsetAsync(counts8, 0, (size_t)NXCD * N * 4, stream);

  detect_layout_kernel<<<1, 64, 0, stream>>>(ei32, flag);

  linear_relu_kernel<<<(N + 255) / 256, 256, 0, stream>>>(x, W, b, h, N);

  hist_xcd_kernel<<<eb, 256, 0, stream>>>(ei32, flag, counts8, rank,
                                          chunk_xcd, N, E);

  scan1_kernel<<<nb1, SCAN_B, 0, stream>>>(counts8, ctot, offsets, partials, N);
  scan2_kernel<<<1, 512, 0, stream>>>(partials, nb1);
  scan3_kernel<<<nb1, SCAN_B, 0, stream>>>(offsets, partials, N);

  place_kernel<<<eb, 256, 0, stream>>>(ei32, flag, offsets, counts8, rank,
                                       chunk_xcd, bucket, N, E);

  gather_kernel<<<(N * 64 + 255) / 256, 256, 0, stream>>>(h, offsets, ctot,
                                                          bucket, out, N);
}

// Round 12
// 277.924 us; speedup vs baseline: 1.1573x; 1.1573x over previous
//
#include <hip/hip_runtime.h>
#include <hip/hip_bf16.h>
#include <hip/hip_fp16.h>

#define DIM 64
#define SCAN_B 256

// ---------------- Kernel 0: detect edge_index element width ----------------
__global__ void detect_layout_kernel(const int* __restrict__ ei32,
                                     int* __restrict__ flag) {
  int v = ei32[2 * threadIdx.x + 1];
  unsigned long long m = __ballot(v != 0);
  if (threadIdx.x == 0) *flag = (m == 0ULL) ? 1 : 0;  // 1 => int64 layout
}

__device__ __forceinline__ int load_idx(const int* ei32, int is64, size_t pos) {
  return is64 ? ei32[2 * pos] : ei32[pos];
}

// ---------------- Kernel 1 (fused): linear_relu ∥ hist_rank ----------------
// Blocks [0, nbLin): h = relu(x @ W^T + b), stored FP16 (halves gather's
// L2-miss traffic, the round-11 wall). Blocks [nbLin, ...): histogram +
// per-edge rank (device-scope returning atomic, coalesced rank stream).
__global__ __launch_bounds__(256) void lin_hist_kernel(
    const float* __restrict__ x, const float* __restrict__ W,
    const float* __restrict__ b, __half* __restrict__ h, int N, int nbLin,
    const int* __restrict__ ei32, const int* __restrict__ flag,
    int* __restrict__ counts, int* __restrict__ rank, int E) {
  __shared__ float Ws[DIM * DIM];
  __shared__ float bs[DIM];

  if (blockIdx.x >= nbLin) {
    // ---- hist_rank path ----
    int e = (blockIdx.x - nbLin) * 256 + threadIdx.x;
    if (e < E) {
      int src = load_idx(ei32, *flag, (size_t)e);
      int r = atomicAdd(&counts[src], 1);
      __builtin_nontemporal_store(r, &rank[e]);
    }
    return;
  }

  // ---- linear_relu path ----
  for (int i = threadIdx.x; i < DIM * DIM; i += 256) Ws[i] = W[i];
  if (threadIdx.x < DIM) bs[threadIdx.x] = b[threadIdx.x];
  __syncthreads();

  int row = blockIdx.x * 256 + threadIdx.x;
  if (row >= N) return;

  const float4* xr = (const float4*)(x + (size_t)row * DIM);
  float acc[DIM];
#pragma unroll
  for (int o = 0; o < DIM; ++o) acc[o] = bs[o];

#pragma unroll
  for (int i4 = 0; i4 < DIM / 4; ++i4) {
    float4 xv = xr[i4];
#pragma unroll
    for (int o = 0; o < DIM; ++o) {
      const float* wrow = &Ws[o * DIM + i4 * 4];
      acc[o] = fmaf(xv.x, wrow[0], acc[o]);
      acc[o] = fmaf(xv.y, wrow[1], acc[o]);
      acc[o] = fmaf(xv.z, wrow[2], acc[o]);
      acc[o] = fmaf(xv.w, wrow[3], acc[o]);
    }
  }

  // Store row as fp16 (RTNE), 4 halfs per 8B store.
  ushort4* hr = (ushort4*)(h + (size_t)row * DIM);
#pragma unroll
  for (int o4 = 0; o4 < DIM / 4; ++o4) {
    ushort4 v;
    v.x = __half_as_ushort(__float2half(fmaxf(acc[o4 * 4 + 0], 0.0f)));
    v.y = __half_as_ushort(__float2half(fmaxf(acc[o4 * 4 + 1], 0.0f)));
    v.z = __half_as_ushort(__float2half(fmaxf(acc[o4 * 4 + 2], 0.0f)));
    v.w = __half_as_ushort(__float2half(fmaxf(acc[o4 * 4 + 3], 0.0f)));
    hr[o4] = v;
  }
}

// ---------------- Scan (3 kernels): offsets = exclusive_scan(counts) -------
__global__ void scan1_kernel(const int* __restrict__ counts,
                             int* __restrict__ offsets,
                             int* __restrict__ partials, int N) {
  __shared__ int s[SCAN_B];
  int t = threadIdx.x;
  int i = blockIdx.x * SCAN_B + t;
  int v = (i < N) ? counts[i] : 0;
  s[t] = v;
  __syncthreads();
  for (int off = 1; off < SCAN_B; off <<= 1) {
    int add = (t >= off) ? s[t - off] : 0;
    __syncthreads();
    s[t] += add;
    __syncthreads();
  }
  if (i < N) offsets[i] = s[t] - v;  // exclusive within block
  if (t == SCAN_B - 1) partials[blockIdx.x] = s[t];
}

__global__ void scan2_kernel(int* __restrict__ partials, int nb) {
  __shared__ int s[512];
  int t = threadIdx.x;
  int v = (t < nb) ? partials[t] : 0;
  s[t] = v;
  __syncthreads();
  for (int off = 1; off < 512; off <<= 1) {
    int add = (t >= off) ? s[t - off] : 0;
    __syncthreads();
    s[t] += add;
    __syncthreads();
  }
  if (t < nb) partials[t] = s[t] - v;  // exclusive
}

__global__ void scan3_kernel(int* __restrict__ offsets,
                             const int* __restrict__ partials, int N) {
  int i = blockIdx.x * SCAN_B + threadIdx.x;
  if (i < N) offsets[i] += partials[blockIdx.x];
}

// ---------------- Kernel 2: place (atomic-free scatter) ----------------
// PLAIN store: nt-store forced 64B write-through per 4B store (round-10:
// 106 MB WRITE). Write-back L2 + masked writeback coalesces node-contiguous
// bucket lines instead.
__global__ __launch_bounds__(256) void place_kernel(
    const int* __restrict__ ei32, const int* __restrict__ flag,
    const int* __restrict__ offsets, const int* __restrict__ rank,
    int* __restrict__ bucket, int E) {
  int e = blockIdx.x * 256 + threadIdx.x;
  if (e >= E) return;
  int is64 = *flag;
  int src = load_idx(ei32, is64, (size_t)e);
  int tgt = load_idx(ei32, is64, (size_t)E + e);
  int r = __builtin_nontemporal_load(&rank[e]);
  bucket[offsets[src] + r] = tgt;
}

// ---------------- Kernel 3: per-node gather + mean ----------------
// One wave per node; lane = feature dim; 8 independent fp16 loads in flight.
// fp16 h: rows are 128 B (2 lines) instead of 256 B (4) -> half the
// L2-miss traffic and half the line-touch count of the round-11 plateau.
__global__ __launch_bounds__(256) void gather_kernel(
    const __half* __restrict__ h, const int* __restrict__ offsets,
    const int* __restrict__ counts, const int* __restrict__ bucket,
    float* __restrict__ out, int N) {
  int wid = (blockIdx.x * 256 + threadIdx.x) >> 6;
  int lane = threadIdx.x & 63;
  if (wid >= N) return;

  int deg = counts[wid];
  int start = offsets[wid];
  float a0 = 0.f, a1 = 0.f, a2 = 0.f, a3 = 0.f;
  float a4 = 0.f, a5 = 0.f, a6 = 0.f, a7 = 0.f;

  for (int j0 = 0; j0 < deg; j0 += 64) {
    int m = min(deg - j0, 64);
    int t = (lane < m) ? __builtin_nontemporal_load(&bucket[start + j0 + lane])
                       : 0;
    int j = 0;
    for (; j + 8 <= m; j += 8) {
      int t0 = __shfl(t, j);
      int t1 = __shfl(t, j + 1);
      int t2 = __shfl(t, j + 2);
      int t3 = __shfl(t, j + 3);
      int t4 = __shfl(t, j + 4);
      int t5 = __shfl(t, j + 5);
      int t6 = __shfl(t, j + 6);
      int t7 = __shfl(t, j + 7);
      float v0 = __half2float(h[(size_t)t0 * DIM + lane]);
      float v1 = __half2float(h[(size_t)t1 * DIM + lane]);
      float v2 = __half2float(h[(size_t)t2 * DIM + lane]);
      float v3 = __half2float(h[(size_t)t3 * DIM + lane]);
      float v4 = __half2float(h[(size_t)t4 * DIM + lane]);
      float v5 = __half2float(h[(size_t)t5 * DIM + lane]);
      float v6 = __half2float(h[(size_t)t6 * DIM + lane]);
      float v7 = __half2float(h[(size_t)t7 * DIM + lane]);
      a0 += v0; a1 += v1; a2 += v2; a3 += v3;
      a4 += v4; a5 += v5; a6 += v6; a7 += v7;
    }
    for (; j < m; ++j) {
      int tj = __shfl(t, j);
      a0 += __half2float(h[(size_t)tj * DIM + lane]);
    }
  }

  float c = (float)max(deg, 1);
  float acc = ((a0 + a1) + (a2 + a3)) + ((a4 + a5) + (a6 + a7));
  __builtin_nontemporal_store(acc / c, &out[(size_t)wid * DIM + lane]);
}

extern "C" void kernel_launch(void* const* d_in, const int* in_sizes, int n_in,
                              void* d_out, int out_size, void* d_ws, size_t ws_size,
                              hipStream_t stream) {
  const float* x = (const float*)d_in[0];
  const int* ei32 = (const int*)d_in[1];
  const float* W = (const float*)d_in[2];
  const float* b = (const float*)d_in[3];

  const int N = in_sizes[0] / DIM;  // 100000
  const int E = in_sizes[1] / 2;    // 1600000

  float* out = (float*)d_out;
  // rank[] borrows d_out (free scratch until gather writes the final output).
  int* rank = (int*)d_out;

  // Workspace: [bucket E][counts N][offsets N][partials 512][flag][h fp16]
  char* p = (char*)d_ws;
  int* bucket = (int*)p;   p += (size_t)E * 4;
  int* counts = (int*)p;   p += (size_t)N * 4;
  int* offsets = (int*)p;  p += (size_t)N * 4;
  int* partials = (int*)p; p += 512 * 4;
  int* flag = (int*)p;     p += 16;
  p = (char*)(((uintptr_t)p + 15) & ~(uintptr_t)15);
  __half* h = (__half*)p;  // N*DIM halfs = 12.8 MB

  const int nb1 = (N + SCAN_B - 1) / SCAN_B;  // 391
  const int eb = (E + 255) / 256;             // 6250
  const int nbLin = (N + 255) / 256;          // 391

  hipMemsetAsync(counts, 0, (size_t)N * 4, stream);

  detect_layout_kernel<<<1, 64, 0, stream>>>(ei32, flag);

  lin_hist_kernel<<<nbLin + eb, 256, 0, stream>>>(x, W, b, h, N, nbLin, ei32,
                                                  flag, counts, rank, E);

  scan1_kernel<<<nb1, SCAN_B, 0, stream>>>(counts, offsets, partials, N);
  scan2_kernel<<<1, 512, 0, stream>>>(partials, nb1);
  scan3_kernel<<<nb1, SCAN_B, 0, stream>>>(offsets, partials, N);

  place_kernel<<<eb, 256, 0, stream>>>(ei32, flag, offsets, rank, bucket, E);

  gather_kernel<<<(N * 64 + 255) / 256, 256, 0, stream>>>(h, offsets, counts,
                                                          bucket, out, N);
}